// Round 9
// baseline (396.189 us; speedup 1.0000x reference)
//
#include <hip/hip_runtime.h>
#include <hip/hip_fp16.h>

// LightGCN 3-layer propagation. out layout: [4, N_NODES, DIM] f32.
//   layer 0 = embeddings (copy); layer l = SpMM(layer l-1).
//
// Ledger:
//  R4-R8: scatter fight. dst-ranges(blockIdx%8)+NT loads = best (WRITE 54.6
//      MB, ~60us); residual write-amp structural. Atomic rule: per-address
//      returning-atomic multiplicity <= tens (R5: 410ns/op serialized/addr).
//  R8: hex spmm (16 chains) < oct (8) -> spmm throughput- not latency-bound.
//  R10: fp16 mirror: 393->366, absmax 0.25. Byte-halving saved only ~9us/l
//      -> spmm bound by random LINE traffic, not bytes.
//  R11: src-range-ordered CSR: NEUTRAL (374). With deg~12 a node's segment
//      is consumed in 1-2 concurrent rounds -> order can't localize. Per-XCD
//      reuse = 150K gathers / 200K lines < 1 -> 102 MB/layer L3->L2 traffic
//      is irreducible for random graphs. spmm floor ~45-55us/layer.
//  R12 (this round): revert build to R10 (simple hist+scan, -8us) and stop
//      polluting L2 in spmm: NT loads for pairs stream, NT store for yh
//      mirror -> L2 capacity reserved for x_h gather lines.

#define N_NODES 100000
#define DIM 64
#define SCAN_CHUNK 1024

#define NR 8                              // dst ranges (XCD round-robin)
#define RSIZE ((N_NODES + NR - 1) / NR)   // 12500 nodes per range
#define SLICES 128                        // edge slices per range

typedef int   vint4   __attribute__((ext_vector_type(4)));
typedef int   vint2   __attribute__((ext_vector_type(2)));
typedef float vfloat4 __attribute__((ext_vector_type(4)));

union HU { unsigned u; __half2 h; };

// ---------------- layer 0: copy f32 + build fp16 mirror ----------------
__global__ void convert_kernel(const float* __restrict__ emb, float* __restrict__ out0,
                               unsigned short* __restrict__ xh0, int n8) {
    int i = blockIdx.x * blockDim.x + threadIdx.x;   // 8 floats per thread
    if (i >= n8) return;
    const vfloat4* e4 = (const vfloat4*)emb;
    vfloat4 a = __builtin_nontemporal_load(e4 + 2 * i);
    vfloat4 b = __builtin_nontemporal_load(e4 + 2 * i + 1);
    vfloat4* o4 = (vfloat4*)out0;
    __builtin_nontemporal_store(a, o4 + 2 * i);
    __builtin_nontemporal_store(b, o4 + 2 * i + 1);
    HU c0, c1, c2, c3;
    c0.h = __float22half2_rn(make_float2(a[0], a[1]));
    c1.h = __float22half2_rn(make_float2(a[2], a[3]));
    c2.h = __float22half2_rn(make_float2(b[0], b[1]));
    c3.h = __float22half2_rn(make_float2(b[2], b[3]));
    vint4 p = { (int)c0.u, (int)c1.u, (int)c2.u, (int)c3.u };
    ((vint4*)xh0)[i] = p;
}

// ---------------- CSR build (R10-proven) ----------------

__global__ void hist_kernel(const int* __restrict__ edst, int* __restrict__ deg, int E) {
    int i = blockIdx.x * blockDim.x + threadIdx.x;
    int nv = E >> 2;
    if (i < nv) {
        vint4 d = __builtin_nontemporal_load(((const vint4*)edst) + i);
        atomicAdd(&deg[d[0]], 1);
        atomicAdd(&deg[d[1]], 1);
        atomicAdd(&deg[d[2]], 1);
        atomicAdd(&deg[d[3]], 1);
    }
    if (i == 0) {
        for (int e = nv << 2; e < E; ++e) atomicAdd(&deg[edst[e]], 1);
    }
}

__global__ void scan1_kernel(const int* __restrict__ src, int* __restrict__ dst,
                             int* __restrict__ bsum, int n) {
    __shared__ int sdata[256];
    int tid = threadIdx.x;
    int base = blockIdx.x * SCAN_CHUNK + tid * 4;
    int v[4];
    #pragma unroll
    for (int i = 0; i < 4; ++i) v[i] = (base + i < n) ? src[base + i] : 0;
    int tsum = v[0] + v[1] + v[2] + v[3];
    sdata[tid] = tsum;
    __syncthreads();
    for (int d = 1; d < 256; d <<= 1) {
        int t = (tid >= d) ? sdata[tid - d] : 0;
        __syncthreads();
        sdata[tid] += t;
        __syncthreads();
    }
    int excl = sdata[tid] - tsum;
    if (tid == 255) bsum[blockIdx.x] = sdata[255];
    int run = excl;
    #pragma unroll
    for (int i = 0; i < 4; ++i) {
        if (base + i < n) dst[base + i] = run;
        run += v[i];
    }
}

__global__ void scan2_kernel(int* __restrict__ bsum, int nb) {
    __shared__ int s[128];
    int tid = threadIdx.x;
    int v = (tid < nb) ? bsum[tid] : 0;
    s[tid] = v;
    __syncthreads();
    for (int d = 1; d < 128; d <<= 1) {
        int t = (tid >= d) ? s[tid - d] : 0;
        __syncthreads();
        s[tid] += t;
        __syncthreads();
    }
    if (tid < nb) bsum[tid] = s[tid] - v;   // exclusive
}

// Adds block prefix; seeds cur = off so scatter needs no off gather.
__global__ void scan3_kernel(int* __restrict__ off, int* __restrict__ cur,
                             const int* __restrict__ bsum, int n) {
    int i = blockIdx.x * blockDim.x + threadIdx.x;
    if (i < n) {
        int v = off[i] + bsum[i / SCAN_CHUNK];
        off[i] = v;
        cur[i] = v;
    }
}

// R6-proven scatter: dst-range partitioned (blockIdx%8) + NT edge streams.
__global__ void scatter_range_kernel(const int* __restrict__ esrc, const int* __restrict__ edst,
                                     const float* __restrict__ ew, int* __restrict__ cur,
                                     int2* __restrict__ pairs, int E, int chunk) {
    const int r = blockIdx.x & (NR - 1);
    const int s = blockIdx.x / NR;
    const int lo = r * RSIZE;
    const int hi = min(lo + RSIZE, N_NODES);
    const int e0 = s * chunk;
    if (e0 >= E) return;
    const int e1 = min(e0 + chunk, E);
    const int nv = (e1 - e0) >> 2;
    const vint4*   s4 = (const vint4*)(esrc + e0);
    const vint4*   d4 = (const vint4*)(edst + e0);
    const vfloat4* w4 = (const vfloat4*)(ew + e0);
    for (int i = threadIdx.x; i < nv; i += blockDim.x) {
        vint4 dd = __builtin_nontemporal_load(d4 + i);
        vint4 ss = __builtin_nontemporal_load(s4 + i);
        vfloat4 ww = __builtin_nontemporal_load(w4 + i);
        #pragma unroll
        for (int j = 0; j < 4; ++j) {
            int dj = dd[j];
            if (dj >= lo && dj < hi) {
                int p = atomicAdd(&cur[dj], 1);
                int2 pr;
                pr.x = ss[j];
                pr.y = __float_as_int(ww[j]);
                pairs[p] = pr;
            }
        }
    }
    for (int e = e0 + (nv << 2) + threadIdx.x; e < e1; e += blockDim.x) {
        int dj = edst[e];
        if (dj >= lo && dj < hi) {
            int p = atomicAdd(&cur[dj], 1);
            int2 pr;
            pr.x = esrc[e];
            pr.y = __float_as_int(ew[e]);
            pairs[p] = pr;
        }
    }
}

// ---------------- SpMM fp16-gather: one wave per node, oct scheme ----------
// Oct o (lanes 8o..8o+7) handles edges k = o, o+8, ... Lane ol loads ONE
// vint4 = 16 B = 8 halves -> 8 lanes cover the full 128 B fp16 row.
// pairs stream + yh mirror are NT (no L2 allocate): keep L2 capacity for
// the x_h gather lines (the only reused data).

__global__ void spmm_h_kernel(const unsigned short* __restrict__ xh,
                              const int2* __restrict__ pairs,
                              const int* __restrict__ off,
                              const int* __restrict__ deg,
                              float* __restrict__ y,
                              unsigned short* __restrict__ yh) {
    int gtid = blockIdx.x * blockDim.x + threadIdx.x;
    int node = gtid >> 6;
    int lane = threadIdx.x & 63;
    int o  = lane >> 3;
    int ol = lane & 7;
    if (node >= N_NODES) return;
    int s0 = off[node];
    int n  = deg[node];
    float a0 = 0.f, a1 = 0.f, a2 = 0.f, a3 = 0.f;
    float a4 = 0.f, a5 = 0.f, a6 = 0.f, a7 = 0.f;   // dims [8ol, 8ol+8)
    for (int k = o; k < n; k += 8) {
        vint2 prv = __builtin_nontemporal_load((const vint2*)(pairs + s0 + k));
        float w = __int_as_float(prv[1]);
        const vint4* row = (const vint4*)(xh + (size_t)prv[0] * DIM);
        vint4 v = row[ol];                           // 8 lanes x 16 B = 128 B row
        HU c; float2 f;
        c.u = (unsigned)v[0]; f = __half22float2(c.h); a0 += w * f.x; a1 += w * f.y;
        c.u = (unsigned)v[1]; f = __half22float2(c.h); a2 += w * f.x; a3 += w * f.y;
        c.u = (unsigned)v[2]; f = __half22float2(c.h); a4 += w * f.x; a5 += w * f.y;
        c.u = (unsigned)v[3]; f = __half22float2(c.h); a6 += w * f.x; a7 += w * f.y;
    }
    #pragma unroll
    for (int d = 8; d <= 32; d <<= 1) {
        a0 += __shfl_xor(a0, d); a1 += __shfl_xor(a1, d);
        a2 += __shfl_xor(a2, d); a3 += __shfl_xor(a3, d);
        a4 += __shfl_xor(a4, d); a5 += __shfl_xor(a5, d);
        a6 += __shfl_xor(a6, d); a7 += __shfl_xor(a7, d);
    }
    if (o == 0) {
        float* yr = y + (size_t)node * DIM + ol * 8;
        vfloat4 r0 = { a0, a1, a2, a3 };
        vfloat4 r1 = { a4, a5, a6, a7 };
        __builtin_nontemporal_store(r0, (vfloat4*)yr);
        __builtin_nontemporal_store(r1, (vfloat4*)yr + 1);
        HU c0, c1, c2, c3;
        c0.h = __float22half2_rn(make_float2(a0, a1));
        c1.h = __float22half2_rn(make_float2(a2, a3));
        c2.h = __float22half2_rn(make_float2(a4, a5));
        c3.h = __float22half2_rn(make_float2(a6, a7));
        vint4 p = { (int)c0.u, (int)c1.u, (int)c2.u, (int)c3.u };
        __builtin_nontemporal_store(p, (vint4*)(yh + (size_t)node * DIM + ol * 8));
    }
}

// ---------------- f32 oct spmm (mid fallback) ----------------

__global__ void spmm_csr_kernel(const float* __restrict__ x,
                                const int2* __restrict__ pairs,
                                const int* __restrict__ off,
                                const int* __restrict__ deg,
                                float* __restrict__ y) {
    int gtid = blockIdx.x * blockDim.x + threadIdx.x;
    int node = gtid >> 6;
    int lane = threadIdx.x & 63;
    int o  = lane >> 3;
    int ol = lane & 7;
    if (node >= N_NODES) return;
    int s0 = off[node];
    int n  = deg[node];
    float4 a0 = make_float4(0.f, 0.f, 0.f, 0.f);
    float4 a1 = a0;
    for (int k = o; k < n; k += 8) {
        int2 pr = pairs[s0 + k];
        float w = __int_as_float(pr.y);
        const float4* row = (const float4*)(x + (size_t)pr.x * DIM);
        float4 v0 = row[ol];
        float4 v1 = row[ol + 8];
        a0.x += w * v0.x; a0.y += w * v0.y; a0.z += w * v0.z; a0.w += w * v0.w;
        a1.x += w * v1.x; a1.y += w * v1.y; a1.z += w * v1.z; a1.w += w * v1.w;
    }
    #pragma unroll
    for (int d = 8; d <= 32; d <<= 1) {
        a0.x += __shfl_xor(a0.x, d); a0.y += __shfl_xor(a0.y, d);
        a0.z += __shfl_xor(a0.z, d); a0.w += __shfl_xor(a0.w, d);
        a1.x += __shfl_xor(a1.x, d); a1.y += __shfl_xor(a1.y, d);
        a1.z += __shfl_xor(a1.z, d); a1.w += __shfl_xor(a1.w, d);
    }
    if (o == 0) {
        vfloat4* yrow = (vfloat4*)(y + (size_t)node * DIM);
        vfloat4 r0 = { a0.x, a0.y, a0.z, a0.w };
        vfloat4 r1 = { a1.x, a1.y, a1.z, a1.w };
        __builtin_nontemporal_store(r0, yrow + ol);
        __builtin_nontemporal_store(r1, yrow + ol + 8);
    }
}

// ---------------- atomic fallback ----------------

__global__ void spmm_atomic_kernel(const float* __restrict__ x, const float* __restrict__ ew,
                                   const int* __restrict__ esrc, const int* __restrict__ edst,
                                   float* __restrict__ y, int n_edges) {
    long long tid = (long long)blockIdx.x * blockDim.x + threadIdx.x;
    int e = (int)(tid >> 6);
    int d = (int)(tid & 63);
    if (e >= n_edges) return;
    int s = esrc[e]; int t = edst[e]; float w = ew[e];
    atomicAdd(&y[(long long)t * DIM + d], w * x[(long long)s * DIM + d]);
}

extern "C" void kernel_launch(void* const* d_in, const int* in_sizes, int n_in,
                              void* d_out, int out_size, void* d_ws, size_t ws_size,
                              hipStream_t stream) {
    const float* emb  = (const float*)d_in[0];
    const float* ew   = (const float*)d_in[1];
    const int*   esrc = (const int*)d_in[2];
    const int*   edst = (const int*)d_in[3];
    float* out = (float*)d_out;

    const int E = in_sizes[1];
    const size_t layer_elems = (size_t)N_NODES * DIM;

    const size_t need_h   = (size_t)E * 8 + 2 * layer_elems * 2 + (size_t)3 * N_NODES * 4 + 1024;
    const size_t need_f32 = (size_t)E * 8 + (size_t)3 * N_NODES * 4 + 1024;

    if (ws_size >= need_h && E >= 4) {
        char* w = (char*)d_ws;
        int2* pairs = (int2*)w;
        unsigned short* xh0 = (unsigned short*)(w + (size_t)E * 8);
        unsigned short* xh1 = xh0 + layer_elems;
        int* deg  = (int*)(xh1 + layer_elems);
        int* cur  = deg + N_NODES;
        int* off  = cur + N_NODES;
        int* bsum = off + N_NODES;     // 128 ints

        hipMemsetAsync(deg, 0, (size_t)N_NODES * 4, stream);

        const int n8 = (int)(layer_elems / 8);
        convert_kernel<<<(n8 + 255) / 256, 256, 0, stream>>>(emb, out, xh0, n8);

        const int nv4 = E >> 2;
        hist_kernel<<<(nv4 + 255) / 256, 256, 0, stream>>>(edst, deg, E);

        const int nscan = (N_NODES + SCAN_CHUNK - 1) / SCAN_CHUNK;   // 98
        scan1_kernel<<<nscan, 256, 0, stream>>>(deg, off, bsum, N_NODES);
        scan2_kernel<<<1, 128, 0, stream>>>(bsum, nscan);
        scan3_kernel<<<(N_NODES + 255) / 256, 256, 0, stream>>>(off, cur, bsum, N_NODES);

        const int chunk = (((E + SLICES - 1) / SLICES) + 3) & ~3;
        scatter_range_kernel<<<NR * SLICES, 256, 0, stream>>>(esrc, edst, ew, cur, pairs, E, chunk);

        const int nb = (N_NODES + 3) / 4;   // 4 waves (nodes) per 256-thread block
        unsigned short* xs[2] = { xh0, xh1 };
        for (int l = 1; l <= 3; ++l) {
            spmm_h_kernel<<<nb, 256, 0, stream>>>(
                xs[(l - 1) & 1], pairs, off, deg,
                out + (size_t)l * layer_elems, xs[l & 1]);
        }
    } else if (ws_size >= need_f32 && E >= 4) {
        char* w = (char*)d_ws;
        int2* pairs = (int2*)w;
        int* deg  = (int*)(w + (size_t)E * 8);
        int* cur  = deg + N_NODES;
        int* off  = cur + N_NODES;
        int* bsum = off + N_NODES;

        hipMemcpyAsync(out, emb, layer_elems * sizeof(float), hipMemcpyDeviceToDevice, stream);
        hipMemsetAsync(deg, 0, (size_t)N_NODES * 4, stream);
        const int nv4 = E >> 2;
        hist_kernel<<<(nv4 + 255) / 256, 256, 0, stream>>>(edst, deg, E);
        const int nscan = (N_NODES + SCAN_CHUNK - 1) / SCAN_CHUNK;
        scan1_kernel<<<nscan, 256, 0, stream>>>(deg, off, bsum, N_NODES);
        scan2_kernel<<<1, 128, 0, stream>>>(bsum, nscan);
        scan3_kernel<<<(N_NODES + 255) / 256, 256, 0, stream>>>(off, cur, bsum, N_NODES);
        const int chunk = (((E + SLICES - 1) / SLICES) + 3) & ~3;
        scatter_range_kernel<<<NR * SLICES, 256, 0, stream>>>(esrc, edst, ew, cur, pairs, E, chunk);
        const int nb = (N_NODES + 3) / 4;
        for (int l = 1; l <= 3; ++l) {
            spmm_csr_kernel<<<nb, 256, 0, stream>>>(
                out + (size_t)(l - 1) * layer_elems, pairs, off, deg,
                out + (size_t)l * layer_elems);
        }
    } else {
        hipMemcpyAsync(out, emb, layer_elems * sizeof(float), hipMemcpyDeviceToDevice, stream);
        hipMemsetAsync(out + layer_elems, 0, 3 * layer_elems * sizeof(float), stream);
        const long long total_threads = (long long)E * 64;
        const int blocks = (int)((total_threads + 255) / 256);
        for (int l = 1; l <= 3; ++l) {
            spmm_atomic_kernel<<<blocks, 256, 0, stream>>>(
                out + (size_t)(l - 1) * layer_elems, ew, esrc, edst,
                out + (size_t)l * layer_elems, E);
        }
    }
}

// Round 10
// 369.931 us; speedup vs baseline: 1.0710x; 1.0710x over previous
//
#include <hip/hip_runtime.h>
#include <hip/hip_fp16.h>

// LightGCN 3-layer propagation. out layout: [4, N_NODES, DIM] f32.
//   layer 0 = embeddings (copy); layer l = SpMM(layer l-1).
//
// Ledger:
//  R4-R8: scatter fight. dst-ranges(blockIdx%8)+NT edge loads = best (WRITE
//      54.6 MB); residual write-amp structural. Atomic rule: per-address
//      returning-atomic multiplicity <= tens (R5: ~410ns/op serialized).
//  R8: hex spmm (16 chains) < oct (8) -> spmm throughput- not latency-bound.
//  R10: fp16 mirror spmm: 366us total, absmax 0.25. BEST.
//  R11: src-range-ordered CSR: neutral (deg~12 consumed concurrently; order
//      can't localize). Per-XCD gather reuse < 1 -> ~100 MB/layer L3->L2
//      random-line traffic irreducible. spmm floor ~50us/layer.
//  R12: NT pairs-load + NT yh-store in spmm: REGRESSED 396 (+10us/layer).
//      yh is next layer's gather source (NT = cold gathers); pairs lines are
//      re-read 8x/line by octs (NT defeats L1/L2). NT only for write-once-
//      never-reread (y) and read-once streams (build stage). REVERTED.
//  R13 (this round): R10 verbatim + SLICES 128->256 for scatter. Scatter ran
//      at 37% occupancy (16 waves/CU) with 4 serial returning-atomic chains
//      per thread; 2048 blocks doubles chains in flight. Merge mechanism
//      untouched (same per-range regions, same read volume).

#define N_NODES 100000
#define DIM 64
#define SCAN_CHUNK 1024

#define NR 8                              // dst ranges (XCD round-robin)
#define RSIZE ((N_NODES + NR - 1) / NR)   // 12500 nodes per range
#define SLICES 256                        // edge slices per range (R13: was 128)

typedef int   vint4   __attribute__((ext_vector_type(4)));
typedef float vfloat4 __attribute__((ext_vector_type(4)));

union HU { unsigned u; __half2 h; };

// ---------------- layer 0: copy f32 + build fp16 mirror ----------------
__global__ void convert_kernel(const float* __restrict__ emb, float* __restrict__ out0,
                               unsigned short* __restrict__ xh0, int n8) {
    int i = blockIdx.x * blockDim.x + threadIdx.x;   // 8 floats per thread
    if (i >= n8) return;
    const vfloat4* e4 = (const vfloat4*)emb;
    vfloat4 a = __builtin_nontemporal_load(e4 + 2 * i);
    vfloat4 b = __builtin_nontemporal_load(e4 + 2 * i + 1);
    vfloat4* o4 = (vfloat4*)out0;
    __builtin_nontemporal_store(a, o4 + 2 * i);
    __builtin_nontemporal_store(b, o4 + 2 * i + 1);
    HU c0, c1, c2, c3;
    c0.h = __float22half2_rn(make_float2(a[0], a[1]));
    c1.h = __float22half2_rn(make_float2(a[2], a[3]));
    c2.h = __float22half2_rn(make_float2(b[0], b[1]));
    c3.h = __float22half2_rn(make_float2(b[2], b[3]));
    vint4 p = { (int)c0.u, (int)c1.u, (int)c2.u, (int)c3.u };
    ((vint4*)xh0)[i] = p;
}

// ---------------- CSR build (R10-proven) ----------------

__global__ void hist_kernel(const int* __restrict__ edst, int* __restrict__ deg, int E) {
    int i = blockIdx.x * blockDim.x + threadIdx.x;
    int nv = E >> 2;
    if (i < nv) {
        vint4 d = __builtin_nontemporal_load(((const vint4*)edst) + i);
        atomicAdd(&deg[d[0]], 1);
        atomicAdd(&deg[d[1]], 1);
        atomicAdd(&deg[d[2]], 1);
        atomicAdd(&deg[d[3]], 1);
    }
    if (i == 0) {
        for (int e = nv << 2; e < E; ++e) atomicAdd(&deg[edst[e]], 1);
    }
}

__global__ void scan1_kernel(const int* __restrict__ src, int* __restrict__ dst,
                             int* __restrict__ bsum, int n) {
    __shared__ int sdata[256];
    int tid = threadIdx.x;
    int base = blockIdx.x * SCAN_CHUNK + tid * 4;
    int v[4];
    #pragma unroll
    for (int i = 0; i < 4; ++i) v[i] = (base + i < n) ? src[base + i] : 0;
    int tsum = v[0] + v[1] + v[2] + v[3];
    sdata[tid] = tsum;
    __syncthreads();
    for (int d = 1; d < 256; d <<= 1) {
        int t = (tid >= d) ? sdata[tid - d] : 0;
        __syncthreads();
        sdata[tid] += t;
        __syncthreads();
    }
    int excl = sdata[tid] - tsum;
    if (tid == 255) bsum[blockIdx.x] = sdata[255];
    int run = excl;
    #pragma unroll
    for (int i = 0; i < 4; ++i) {
        if (base + i < n) dst[base + i] = run;
        run += v[i];
    }
}

__global__ void scan2_kernel(int* __restrict__ bsum, int nb) {
    __shared__ int s[128];
    int tid = threadIdx.x;
    int v = (tid < nb) ? bsum[tid] : 0;
    s[tid] = v;
    __syncthreads();
    for (int d = 1; d < 128; d <<= 1) {
        int t = (tid >= d) ? s[tid - d] : 0;
        __syncthreads();
        s[tid] += t;
        __syncthreads();
    }
    if (tid < nb) bsum[tid] = s[tid] - v;   // exclusive
}

// Adds block prefix; seeds cur = off so scatter needs no off gather.
__global__ void scan3_kernel(int* __restrict__ off, int* __restrict__ cur,
                             const int* __restrict__ bsum, int n) {
    int i = blockIdx.x * blockDim.x + threadIdx.x;
    if (i < n) {
        int v = off[i] + bsum[i / SCAN_CHUNK];
        off[i] = v;
        cur[i] = v;
    }
}

// R6-proven scatter: dst-range partitioned (blockIdx%8) + NT edge streams.
__global__ void scatter_range_kernel(const int* __restrict__ esrc, const int* __restrict__ edst,
                                     const float* __restrict__ ew, int* __restrict__ cur,
                                     int2* __restrict__ pairs, int E, int chunk) {
    const int r = blockIdx.x & (NR - 1);
    const int s = blockIdx.x / NR;
    const int lo = r * RSIZE;
    const int hi = min(lo + RSIZE, N_NODES);
    const int e0 = s * chunk;
    if (e0 >= E) return;
    const int e1 = min(e0 + chunk, E);
    const int nv = (e1 - e0) >> 2;
    const vint4*   s4 = (const vint4*)(esrc + e0);
    const vint4*   d4 = (const vint4*)(edst + e0);
    const vfloat4* w4 = (const vfloat4*)(ew + e0);
    for (int i = threadIdx.x; i < nv; i += blockDim.x) {
        vint4 dd = __builtin_nontemporal_load(d4 + i);
        vint4 ss = __builtin_nontemporal_load(s4 + i);
        vfloat4 ww = __builtin_nontemporal_load(w4 + i);
        #pragma unroll
        for (int j = 0; j < 4; ++j) {
            int dj = dd[j];
            if (dj >= lo && dj < hi) {
                int p = atomicAdd(&cur[dj], 1);
                int2 pr;
                pr.x = ss[j];
                pr.y = __float_as_int(ww[j]);
                pairs[p] = pr;
            }
        }
    }
    for (int e = e0 + (nv << 2) + threadIdx.x; e < e1; e += blockDim.x) {
        int dj = edst[e];
        if (dj >= lo && dj < hi) {
            int p = atomicAdd(&cur[dj], 1);
            int2 pr;
            pr.x = esrc[e];
            pr.y = __float_as_int(ew[e]);
            pairs[p] = pr;
        }
    }
}

// ---------------- SpMM fp16-gather: one wave per node, oct scheme ----------
// R10-exact: plain pairs load (L1/L2-served, 8x reuse per line), plain yh
// store (next layer's gather source must stay cacheable), NT y store only.

__global__ void spmm_h_kernel(const unsigned short* __restrict__ xh,
                              const int2* __restrict__ pairs,
                              const int* __restrict__ off,
                              const int* __restrict__ deg,
                              float* __restrict__ y,
                              unsigned short* __restrict__ yh) {
    int gtid = blockIdx.x * blockDim.x + threadIdx.x;
    int node = gtid >> 6;
    int lane = threadIdx.x & 63;
    int o  = lane >> 3;
    int ol = lane & 7;
    if (node >= N_NODES) return;
    int s0 = off[node];
    int n  = deg[node];
    float a0 = 0.f, a1 = 0.f, a2 = 0.f, a3 = 0.f;
    float a4 = 0.f, a5 = 0.f, a6 = 0.f, a7 = 0.f;   // dims [8ol, 8ol+8)
    for (int k = o; k < n; k += 8) {
        int2 pr = pairs[s0 + k];                     // uniform within oct
        float w = __int_as_float(pr.y);
        const vint4* row = (const vint4*)(xh + (size_t)pr.x * DIM);
        vint4 v = row[ol];                           // 8 lanes x 16 B = 128 B row
        HU c; float2 f;
        c.u = (unsigned)v[0]; f = __half22float2(c.h); a0 += w * f.x; a1 += w * f.y;
        c.u = (unsigned)v[1]; f = __half22float2(c.h); a2 += w * f.x; a3 += w * f.y;
        c.u = (unsigned)v[2]; f = __half22float2(c.h); a4 += w * f.x; a5 += w * f.y;
        c.u = (unsigned)v[3]; f = __half22float2(c.h); a6 += w * f.x; a7 += w * f.y;
    }
    #pragma unroll
    for (int d = 8; d <= 32; d <<= 1) {
        a0 += __shfl_xor(a0, d); a1 += __shfl_xor(a1, d);
        a2 += __shfl_xor(a2, d); a3 += __shfl_xor(a3, d);
        a4 += __shfl_xor(a4, d); a5 += __shfl_xor(a5, d);
        a6 += __shfl_xor(a6, d); a7 += __shfl_xor(a7, d);
    }
    if (o == 0) {
        float* yr = y + (size_t)node * DIM + ol * 8;
        vfloat4 r0 = { a0, a1, a2, a3 };
        vfloat4 r1 = { a4, a5, a6, a7 };
        __builtin_nontemporal_store(r0, (vfloat4*)yr);
        __builtin_nontemporal_store(r1, (vfloat4*)yr + 1);
        HU c0, c1, c2, c3;
        c0.h = __float22half2_rn(make_float2(a0, a1));
        c1.h = __float22half2_rn(make_float2(a2, a3));
        c2.h = __float22half2_rn(make_float2(a4, a5));
        c3.h = __float22half2_rn(make_float2(a6, a7));
        vint4 p = { (int)c0.u, (int)c1.u, (int)c2.u, (int)c3.u };
        *((vint4*)(yh + (size_t)node * DIM + ol * 8)) = p;
    }
}

// ---------------- f32 oct spmm (mid fallback) ----------------

__global__ void spmm_csr_kernel(const float* __restrict__ x,
                                const int2* __restrict__ pairs,
                                const int* __restrict__ off,
                                const int* __restrict__ deg,
                                float* __restrict__ y) {
    int gtid = blockIdx.x * blockDim.x + threadIdx.x;
    int node = gtid >> 6;
    int lane = threadIdx.x & 63;
    int o  = lane >> 3;
    int ol = lane & 7;
    if (node >= N_NODES) return;
    int s0 = off[node];
    int n  = deg[node];
    float4 a0 = make_float4(0.f, 0.f, 0.f, 0.f);
    float4 a1 = a0;
    for (int k = o; k < n; k += 8) {
        int2 pr = pairs[s0 + k];
        float w = __int_as_float(pr.y);
        const float4* row = (const float4*)(x + (size_t)pr.x * DIM);
        float4 v0 = row[ol];
        float4 v1 = row[ol + 8];
        a0.x += w * v0.x; a0.y += w * v0.y; a0.z += w * v0.z; a0.w += w * v0.w;
        a1.x += w * v1.x; a1.y += w * v1.y; a1.z += w * v1.z; a1.w += w * v1.w;
    }
    #pragma unroll
    for (int d = 8; d <= 32; d <<= 1) {
        a0.x += __shfl_xor(a0.x, d); a0.y += __shfl_xor(a0.y, d);
        a0.z += __shfl_xor(a0.z, d); a0.w += __shfl_xor(a0.w, d);
        a1.x += __shfl_xor(a1.x, d); a1.y += __shfl_xor(a1.y, d);
        a1.z += __shfl_xor(a1.z, d); a1.w += __shfl_xor(a1.w, d);
    }
    if (o == 0) {
        vfloat4* yrow = (vfloat4*)(y + (size_t)node * DIM);
        vfloat4 r0 = { a0.x, a0.y, a0.z, a0.w };
        vfloat4 r1 = { a1.x, a1.y, a1.z, a1.w };
        __builtin_nontemporal_store(r0, yrow + ol);
        __builtin_nontemporal_store(r1, yrow + ol + 8);
    }
}

// ---------------- atomic fallback ----------------

__global__ void spmm_atomic_kernel(const float* __restrict__ x, const float* __restrict__ ew,
                                   const int* __restrict__ esrc, const int* __restrict__ edst,
                                   float* __restrict__ y, int n_edges) {
    long long tid = (long long)blockIdx.x * blockDim.x + threadIdx.x;
    int e = (int)(tid >> 6);
    int d = (int)(tid & 63);
    if (e >= n_edges) return;
    int s = esrc[e]; int t = edst[e]; float w = ew[e];
    atomicAdd(&y[(long long)t * DIM + d], w * x[(long long)s * DIM + d]);
}

extern "C" void kernel_launch(void* const* d_in, const int* in_sizes, int n_in,
                              void* d_out, int out_size, void* d_ws, size_t ws_size,
                              hipStream_t stream) {
    const float* emb  = (const float*)d_in[0];
    const float* ew   = (const float*)d_in[1];
    const int*   esrc = (const int*)d_in[2];
    const int*   edst = (const int*)d_in[3];
    float* out = (float*)d_out;

    const int E = in_sizes[1];
    const size_t layer_elems = (size_t)N_NODES * DIM;

    const size_t need_h   = (size_t)E * 8 + 2 * layer_elems * 2 + (size_t)3 * N_NODES * 4 + 1024;
    const size_t need_f32 = (size_t)E * 8 + (size_t)3 * N_NODES * 4 + 1024;

    if (ws_size >= need_h && E >= 4) {
        char* w = (char*)d_ws;
        int2* pairs = (int2*)w;
        unsigned short* xh0 = (unsigned short*)(w + (size_t)E * 8);
        unsigned short* xh1 = xh0 + layer_elems;
        int* deg  = (int*)(xh1 + layer_elems);
        int* cur  = deg + N_NODES;
        int* off  = cur + N_NODES;
        int* bsum = off + N_NODES;     // 128 ints

        hipMemsetAsync(deg, 0, (size_t)N_NODES * 4, stream);

        const int n8 = (int)(layer_elems / 8);
        convert_kernel<<<(n8 + 255) / 256, 256, 0, stream>>>(emb, out, xh0, n8);

        const int nv4 = E >> 2;
        hist_kernel<<<(nv4 + 255) / 256, 256, 0, stream>>>(edst, deg, E);

        const int nscan = (N_NODES + SCAN_CHUNK - 1) / SCAN_CHUNK;   // 98
        scan1_kernel<<<nscan, 256, 0, stream>>>(deg, off, bsum, N_NODES);
        scan2_kernel<<<1, 128, 0, stream>>>(bsum, nscan);
        scan3_kernel<<<(N_NODES + 255) / 256, 256, 0, stream>>>(off, cur, bsum, N_NODES);

        const int chunk = (((E + SLICES - 1) / SLICES) + 3) & ~3;
        scatter_range_kernel<<<NR * SLICES, 256, 0, stream>>>(esrc, edst, ew, cur, pairs, E, chunk);

        const int nb = (N_NODES + 3) / 4;   // 4 waves (nodes) per 256-thread block
        unsigned short* xs[2] = { xh0, xh1 };
        for (int l = 1; l <= 3; ++l) {
            spmm_h_kernel<<<nb, 256, 0, stream>>>(
                xs[(l - 1) & 1], pairs, off, deg,
                out + (size_t)l * layer_elems, xs[l & 1]);
        }
    } else if (ws_size >= need_f32 && E >= 4) {
        char* w = (char*)d_ws;
        int2* pairs = (int2*)w;
        int* deg  = (int*)(w + (size_t)E * 8);
        int* cur  = deg + N_NODES;
        int* off  = cur + N_NODES;
        int* bsum = off + N_NODES;

        hipMemcpyAsync(out, emb, layer_elems * sizeof(float), hipMemcpyDeviceToDevice, stream);
        hipMemsetAsync(deg, 0, (size_t)N_NODES * 4, stream);
        const int nv4 = E >> 2;
        hist_kernel<<<(nv4 + 255) / 256, 256, 0, stream>>>(edst, deg, E);
        const int nscan = (N_NODES + SCAN_CHUNK - 1) / SCAN_CHUNK;
        scan1_kernel<<<nscan, 256, 0, stream>>>(deg, off, bsum, N_NODES);
        scan2_kernel<<<1, 128, 0, stream>>>(bsum, nscan);
        scan3_kernel<<<(N_NODES + 255) / 256, 256, 0, stream>>>(off, cur, bsum, N_NODES);
        const int chunk = (((E + SLICES - 1) / SLICES) + 3) & ~3;
        scatter_range_kernel<<<NR * SLICES, 256, 0, stream>>>(esrc, edst, ew, cur, pairs, E, chunk);
        const int nb = (N_NODES + 3) / 4;
        for (int l = 1; l <= 3; ++l) {
            spmm_csr_kernel<<<nb, 256, 0, stream>>>(
                out + (size_t)(l - 1) * layer_elems, pairs, off, deg,
                out + (size_t)l * layer_elems);
        }
    } else {
        hipMemcpyAsync(out, emb, layer_elems * sizeof(float), hipMemcpyDeviceToDevice, stream);
        hipMemsetAsync(out + layer_elems, 0, 3 * layer_elems * sizeof(float), stream);
        const long long total_threads = (long long)E * 64;
        const int blocks = (int)((total_threads + 255) / 256);
        for (int l = 1; l <= 3; ++l) {
            spmm_atomic_kernel<<<blocks, 256, 0, stream>>>(
                out + (size_t)(l - 1) * layer_elems, ew, esrc, edst,
                out + (size_t)l * layer_elems, E);
        }
    }
}